// Round 18
// baseline (78.936 us; speedup 1.0000x reference)
//
#include <hip/hip_runtime.h>
#include <hip/hip_bf16.h>

#define NB   32
#define CIN  128
#define COUT 256
#define HH   56
#define WW   56
#define CH   59        // padded B-row length in 16B chunks (944 B = 59*16)

typedef __attribute__((ext_vector_type(8))) short short8;   // 8 bf16 (4 VGPRs)
typedef __attribute__((ext_vector_type(4))) float f32x4;    // MFMA accumulator

// round-to-nearest-even fp32 -> bf16 (raw u16)
__device__ __forceinline__ unsigned short f2bf(float f) {
    unsigned int u = __builtin_bit_cast(unsigned int, f);
    u = u + 0x7fffu + ((u >> 16) & 1u);
    return (unsigned short)(u >> 16);
}

// ---------------------------------------------------------------------------
// Pre-pass: weights OIHW f32 -> wt2 in EXACT MFMA A-fragment order:
//   chunk ((s*16 + f)*64 + lane), elem j:  w[o=f*16+r][c=cc*32+g*8+j][tap t]
//   (s = K-step: t = s>>2, cc = s&3;  lane: g = lane>>4, r = lane&15)
// A wave's per-step fragment load is ONE coalesced global_load_dwordx4,
// L1/L2-resident (576 KB total, same stream for every block).
// ---------------------------------------------------------------------------
__global__ __launch_bounds__(256) void wpose_kernel(const float* __restrict__ w,
                                                    unsigned short* __restrict__ wt2) {
    int q = blockIdx.x * 256 + threadIdx.x;
    if (q >= 36 * 16 * 64 * 8) return;
    int j = q & 7;
    int l = (q >> 3) & 63;
    int f = (q >> 9) & 15;
    int s = q >> 13;
    int g = l >> 4, r = l & 15;
    int t = s >> 2, cc = s & 3;
    int o = f * 16 + r;
    int c = cc * 32 + g * 8 + j;
    wt2[q] = f2bf(w[((size_t)o * CIN + c) * 9 + t]);
}

// ---------------------------------------------------------------------------
// Main conv: block = 256 Cout x 224 spatial (4 output rows h0..h0+3),
// 512 threads = 8 waves as 4(M) x 2(N); wave = 64 Cout x 112 cols
// (4 M-frags x 7 N-frags of 16x16x32; Fm=4/Fn=7 = the measured balanced
// point for A/B port traffic). 36 K-steps, BARRIER-FREE (single barrier
// total -- every barriered variant measured worse across r2..r17).
//
// Final consolidation of the 8-variant ablation:
//   * plain direct-global-A K-loop (r5: the measured-best compute loop;
//     A-ring r13 and B-dbuf r15 both measured neutral -> removed)
//   * fused float4-vectorized transpose (r12; scalar version was -45us)
//   * pad-only LDS zeroing (r16 trim; its mid-loop barrier is NOT carried)
//   B: x rows h0-1..h0+4, chunk ((row*16+gc)*59 + wpos), 8 ch each;
//      wpos 0/57 + OOB rows zeroed. K-loop B addressing = 16-bit immediates
//      off per-lane bbase (kh*15104 + cc*3776 + kw*16).
// LDS = 90624 B.
// ---------------------------------------------------------------------------
__global__ __launch_bounds__(512) void conv_mfma_kernel(
        const float* __restrict__ x,
        const unsigned short* __restrict__ wt2,
        const float* __restrict__ bias,
        float* __restrict__ out) {
    __shared__ unsigned short ldsB[6 * 16 * CH * 8];    // 90624 B

    const int tid  = threadIdx.x;
    const int h0   = blockIdx.x * 4, n = blockIdx.y;
    const int wid  = tid >> 6, lane = tid & 63;
    const int wm   = wid >> 1, wn = wid & 1;            // 4M x 2N wave grid
    const int g    = lane >> 4, r = lane & 15;

    const uint4 z = {0u, 0u, 0u, 0u};

    // ---- zero ONLY pad chunks (wpos 0,57,58 all rows) + OOB rows ----
    if (tid < 288) {                        // 6 rows x 16 gc x {0,57,58}
        int row = tid / 48, sub = tid % 48;
        int gc = sub / 3, k3 = sub % 3;
        int wp = (k3 == 0) ? 0 : (56 + k3);
        *(uint4*)&ldsB[(size_t)((row * 16 + gc) * CH + wp) * 8] = z;
    }
    if (h0 == 0) {                          // input row h0-1 OOB -> row 0 = 0
        for (int i = tid; i < 16 * CH; i += 512)
            *(uint4*)&ldsB[(size_t)i * 8] = z;
    }
    if (h0 == 52) {                         // input row h0+4 OOB -> row 5 = 0
        for (int i = tid; i < 16 * CH; i += 512)
            *(uint4*)&ldsB[(size_t)(5 * 16 * CH + i) * 8] = z;
    }

    // ---- fused transpose, float4-vectorized: unit = (row, cp, w4) ----
    {
        const float* xn = x + (size_t)n * CIN * HH * WW;
        for (int i = tid; i < 6 * 64 * 14; i += 512) {   // 5376 units
            int w4  = i % 14;
            int t1  = i / 14;
            int cp  = t1 & 63;                  // channel pair: c = 2cp, 2cp+1
            int row = t1 >> 6;                  // 0..5 -> input row h0+row-1
            int hs  = h0 + row - 1;
            if ((unsigned)hs < HH) {
                const float* p = xn + ((size_t)(2 * cp) * HH + hs) * WW + 4 * w4;
                float4 va = *(const float4*)p;
                float4 vb = *(const float4*)(p + HH * WW);
                int gc = cp >> 2, e = cp & 3;
                #pragma unroll
                for (int j = 0; j < 4; ++j) {
                    int wpos = 4 * w4 + j + 1;
                    unsigned int pk = (unsigned int)f2bf(((const float*)&va)[j])
                                    | ((unsigned int)f2bf(((const float*)&vb)[j]) << 16);
                    ((unsigned int*)ldsB)[((row * 16 + gc) * CH + wpos) * 4 + e] = pk;
                }
            }
        }
    }
    __syncthreads();    // B ready; the only barrier

    // per-lane B base pointers for the 7 N-fragments
    const unsigned short* bbase[7];
    #pragma unroll
    for (int ni = 0; ni < 7; ++ni) {
        int c  = ni * 16 + r;
        int hr = (c >= 56) ? 1 : 0;
        int lo = hr * (16 * CH) + (c - hr * 56);
        bbase[ni] = &ldsB[(size_t)((wn * 32 + g) * CH + lo) * 8];
    }

    f32x4 acc[4][7];
    #pragma unroll
    for (int mi = 0; mi < 4; ++mi)
        #pragma unroll
        for (int ni = 0; ni < 7; ++ni)
            #pragma unroll
            for (int v = 0; v < 4; ++v) acc[mi][ni][v] = 0.f;

    // wave's A base: fragment f = wm*4 + mi, chunk ((s*16+f)*64 + lane)
    const short8* abase = (const short8*)wt2 + (size_t)(wm * 4) * 64 + lane;

    #pragma unroll
    for (int t = 0; t < 9; ++t) {
        const int kh = t / 3, kw = t - 3 * (t / 3);
        #pragma unroll
        for (int cc = 0; cc < 4; ++cc) {
            const int s = t * 4 + cc;
            const int boff = kh * 15104 + cc * 3776 + kw * 16;

            short8 a[4];
            #pragma unroll
            for (int mi = 0; mi < 4; ++mi)
                a[mi] = abase[(size_t)s * 1024 + mi * 64];

            short8 b[7];
            #pragma unroll
            for (int ni = 0; ni < 7; ++ni)
                b[ni] = *(const short8*)((const char*)bbase[ni] + boff);

            #pragma unroll
            for (int mi = 0; mi < 4; ++mi)
                #pragma unroll
                for (int ni = 0; ni < 7; ++ni)
                    acc[mi][ni] = __builtin_amdgcn_mfma_f32_16x16x32_bf16(
                        a[mi], b[ni], acc[mi][ni], 0, 0, 0);
        }
    }

    // ---- epilogue: D col = r (spatial), row = g*4+v (Cout within frag) ----
    #pragma unroll
    for (int mi = 0; mi < 4; ++mi) {
        const int o0 = wm * 64 + mi * 16 + 4 * g;
        const float4 bv = *(const float4*)&bias[o0];
        #pragma unroll
        for (int ni = 0; ni < 7; ++ni) {
            const int c  = ni * 16 + r;
            const int hr = (c >= 56) ? 1 : 0;
            const int h  = h0 + wn * 2 + hr;
            const int w  = c - hr * 56;
            #pragma unroll
            for (int v = 0; v < 4; ++v) {
                out[((size_t)(n * COUT + o0 + v) * HH + h) * WW + w] =
                    acc[mi][ni][v] + ((const float*)&bv)[v];
            }
        }
    }
}

extern "C" void kernel_launch(void* const* d_in, const int* in_sizes, int n_in,
                              void* d_out, int out_size, void* d_ws, size_t ws_size,
                              hipStream_t stream) {
    const float* x  = (const float*)d_in[0];   // (32,128,56,56)
    const float* wk = (const float*)d_in[1];   // (256,128,3,3)
    const float* b  = (const float*)d_in[2];   // (256,)
    float* out = (float*)d_out;

    unsigned short* wt2 = (unsigned short*)d_ws;   // 294,912 elems = 590 KB

    wpose_kernel<<<(36 * 16 * 64 * 8 + 255) / 256, 256, 0, stream>>>(wk, wt2);
    dim3 gc(14, NB);                               // 4 output rows per block
    conv_mfma_kernel<<<gc, 512, 0, stream>>>(x, wt2, b, out);
    (void)ws_size; (void)in_sizes; (void)n_in; (void)out_size;
}

// Round 19
// 72.980 us; speedup vs baseline: 1.0816x; 1.0816x over previous
//
#include <hip/hip_runtime.h>
#include <hip/hip_bf16.h>

#define NB   32
#define CIN  128
#define COUT 256
#define HH   56
#define WW   56
#define CH   59        // padded B-row length in 16B chunks (944 = 16*59)

typedef __attribute__((ext_vector_type(8))) short short8;   // 8 bf16 (4 VGPRs)
typedef __attribute__((ext_vector_type(4))) float f32x4;    // MFMA accumulator

// round-to-nearest-even fp32 -> bf16 (raw u16)
__device__ __forceinline__ unsigned short f2bf(float f) {
    unsigned int u = __builtin_bit_cast(unsigned int, f);
    u = u + 0x7fffu + ((u >> 16) & 1u);
    return (unsigned short)(u >> 16);
}

// async global->LDS, 16B per lane; LDS dest = wave-uniform base + lane*16
__device__ __forceinline__ void glds16(const unsigned short* g, unsigned short* l) {
    __builtin_amdgcn_global_load_lds(
        (const __attribute__((address_space(1))) unsigned int*)g,
        (__attribute__((address_space(3))) unsigned int*)l,
        16, 0, 0);
}

// ---------------------------------------------------------------------------
// Pre-pass: weights OIHW f32 -> wt2 in EXACT MFMA A-fragment order:
//   chunk ((s*16 + f)*64 + lane), elem j:  w[o=f*16+r][c=cc*32+g*8+j][tap t]
//   (s = K-step: t = s>>2, cc = s&3;  lane: g = lane>>4, r = lane&15)
// ---------------------------------------------------------------------------
__global__ __launch_bounds__(256) void wpose_kernel(const float* __restrict__ w,
                                                    unsigned short* __restrict__ wt2) {
    int q = blockIdx.x * 256 + threadIdx.x;
    if (q >= 36 * 16 * 64 * 8) return;
    int j = q & 7;
    int l = (q >> 3) & 63;
    int f = (q >> 9) & 15;
    int s = q >> 13;
    int g = l >> 4, r = l & 15;
    int t = s >> 2, cc = s & 3;
    int o = f * 16 + r;
    int c = cc * 32 + g * 8 + j;
    wt2[q] = f2bf(w[((size_t)o * CIN + c) * 9 + t]);
}

// ---------------------------------------------------------------------------
// Main conv (FINAL, = measured-best r15): block = 256 Cout x 224 spatial
// (4 output rows h0..h0+3), 512 threads = 8 waves as 4(M) x 2(N); wave =
// 64 Cout x 112 cols (4 M-frags x 7 N-frags of 16x16x32 -- the unique
// port-balanced point at 2 waves/SIMD). 36 K-steps, barrier-free.
//
//   A: per-wave private LDS ring (2 slots x 4 frags) fed by global_load_lds,
//      ordered by per-wave `s_waitcnt vmcnt(4)` only -- NO s_barrier.
//      (A/B-isolated vs r18: worth ~4 us over direct-global A.)
//   B: x rows h0-1..h0+4 transposed in-block, float4-vectorized, staged ONCE:
//      chunk ((row*16+gc)*59 + wpos), 8 ch; wpos 0/57/58 + OOB rows = 0.
//      All K-loop B addressing = 16-bit ds_read immediates.
//   + distance-1 B-register double-buffer (measured neutral, kept: frees
//     the ds_read->MFMA chain when the scheduler wants it).
// LDS = 90624 (B) + 65536 (A-ring) = 156160 B.
// ---------------------------------------------------------------------------
__global__ __launch_bounds__(512, 2) void conv_mfma_kernel(
        const float* __restrict__ x,
        const unsigned short* __restrict__ wt2,
        const float* __restrict__ bias,
        float* __restrict__ out) {
    __shared__ unsigned short ldsB[6 * 16 * CH * 8];    // 90624 B
    __shared__ unsigned short ldsA[8 * 2 * 2048];       // 65536 B: [wave][slot][4KB]

    const int tid  = threadIdx.x;
    const int h0   = blockIdx.x * 4, n = blockIdx.y;
    const int wid  = tid >> 6, lane = tid & 63;
    const int wm   = wid >> 1, wn = wid & 1;            // 4M x 2N wave grid
    const int g    = lane >> 4, r = lane & 15;

    // ---- zero B chunks (pads + OOB rows stay zero) ----
    for (int i = tid; i < 6 * 16 * CH; i += 512) {
        uint4 z = {0u, 0u, 0u, 0u};
        *(uint4*)&ldsB[(size_t)i * 8] = z;
    }
    __syncthreads();

    // ---- fused transpose, float4-vectorized: unit = (row, cp, w4) ----
    {
        const float* xn = x + (size_t)n * CIN * HH * WW;
        for (int i = tid; i < 6 * 64 * 14; i += 512) {   // 5376 units
            int w4  = i % 14;
            int t1  = i / 14;
            int cp  = t1 & 63;                  // channel pair: c = 2cp, 2cp+1
            int row = t1 >> 6;                  // 0..5 -> input row h0+row-1
            int hs  = h0 + row - 1;
            if ((unsigned)hs < HH) {
                const float* p = xn + ((size_t)(2 * cp) * HH + hs) * WW + 4 * w4;
                float4 va = *(const float4*)p;
                float4 vb = *(const float4*)(p + HH * WW);
                int gc = cp >> 2, e = cp & 3;
                #pragma unroll
                for (int j = 0; j < 4; ++j) {
                    int wpos = 4 * w4 + j + 1;
                    unsigned int pk = (unsigned int)f2bf(((const float*)&va)[j])
                                    | ((unsigned int)f2bf(((const float*)&vb)[j]) << 16);
                    ((unsigned int*)ldsB)[((row * 16 + gc) * CH + wpos) * 4 + e] = pk;
                }
            }
        }
    }

    // ---- A-ring stage: wave wid's 4 frags (f = wm*4+mi) for step s -> slot ----
    unsigned short* aslot = &ldsA[(size_t)wid * 2 * 2048];
    #define STAGE_A(slot, s)                                                    \
        {                                                                       \
            const unsigned short* asrc_ =                                       \
                wt2 + ((size_t)(s) * 16 + wm * 4) * 512 + lane * 8;             \
            unsigned short* adst_ = aslot + (slot) * 2048;                      \
            glds16(asrc_,        adst_);                                        \
            glds16(asrc_ + 512,  adst_ + 512);                                  \
            glds16(asrc_ + 1024, adst_ + 1024);                                 \
            glds16(asrc_ + 1536, adst_ + 1536);                                 \
        }

    STAGE_A(0, 0);
    __syncthreads();    // drains transpose writes AND slot-0 glds; last barrier

    // per-lane B base pointers for the 7 N-fragments
    const unsigned short* bbase[7];
    #pragma unroll
    for (int ni = 0; ni < 7; ++ni) {
        int c  = ni * 16 + r;
        int hr = (c >= 56) ? 1 : 0;
        int lo = hr * (16 * CH) + (c - hr * 56);
        bbase[ni] = &ldsB[(size_t)((wn * 32 + g) * CH + lo) * 8];
    }

    f32x4 acc[4][7];
    #pragma unroll
    for (int mi = 0; mi < 4; ++mi)
        #pragma unroll
        for (int ni = 0; ni < 7; ++ni)
            #pragma unroll
            for (int v = 0; v < 4; ++v) acc[mi][ni][v] = 0.f;

    const unsigned short* aread = aslot + lane * 8;   // + slot*2048 + mi*512

    // ---- distance-1 B-register double-buffer ----
    short8 bcur[7], bnxt[7];
    #define LOAD_B(dst, s_)                                                     \
        {                                                                       \
            const int t_ = (s_) >> 2, cc_ = (s_) & 3;                           \
            const int kh_ = t_ / 3, kw_ = t_ - 3 * (t_ / 3);                    \
            const int boff_ = kh_ * 15104 + cc_ * 3776 + kw_ * 16;              \
            _Pragma("unroll")                                                   \
            for (int ni = 0; ni < 7; ++ni)                                      \
                dst[ni] = *(const short8*)((const char*)bbase[ni] + boff_);     \
        }

    LOAD_B(bcur, 0);

    #pragma unroll
    for (int s = 0; s < 36; ++s) {
        const int p = s & 1;

        if (s < 35) STAGE_A(p ^ 1, s + 1);      // next A slice (async glds)
        if (s < 35) {                           // next B frags (ds_reads issue
            if (p == 0) { LOAD_B(bnxt, s + 1); }//  before this step's MFMAs)
            else        { LOAD_B(bcur, s + 1); }
        }

        // wait: step-s's 4 glds landed (s+1's 4 may stay in flight)
        if (s < 35) asm volatile("s_waitcnt vmcnt(4)" ::: "memory");
        else        asm volatile("s_waitcnt vmcnt(0)" ::: "memory");

        short8 a[4];
        #pragma unroll
        for (int mi = 0; mi < 4; ++mi)
            a[mi] = *(const short8*)(aread + p * 2048 + mi * 512);

        #pragma unroll
        for (int mi = 0; mi < 4; ++mi)
            #pragma unroll
            for (int ni = 0; ni < 7; ++ni)
                acc[mi][ni] = __builtin_amdgcn_mfma_f32_16x16x32_bf16(
                    a[mi], (p == 0) ? bcur[ni] : bnxt[ni], acc[mi][ni], 0, 0, 0);
    }

    // ---- epilogue: D col = r (spatial), row = g*4+v (Cout within frag) ----
    #pragma unroll
    for (int mi = 0; mi < 4; ++mi) {
        const int o0 = wm * 64 + mi * 16 + 4 * g;
        const float4 bv = *(const float4*)&bias[o0];
        #pragma unroll
        for (int ni = 0; ni < 7; ++ni) {
            const int c  = ni * 16 + r;
            const int hr = (c >= 56) ? 1 : 0;
            const int h  = h0 + wn * 2 + hr;
            const int w  = c - hr * 56;
            #pragma unroll
            for (int v = 0; v < 4; ++v) {
                out[((size_t)(n * COUT + o0 + v) * HH + h) * WW + w] =
                    acc[mi][ni][v] + ((const float*)&bv)[v];
            }
        }
    }
}

extern "C" void kernel_launch(void* const* d_in, const int* in_sizes, int n_in,
                              void* d_out, int out_size, void* d_ws, size_t ws_size,
                              hipStream_t stream) {
    const float* x  = (const float*)d_in[0];   // (32,128,56,56)
    const float* wk = (const float*)d_in[1];   // (256,128,3,3)
    const float* b  = (const float*)d_in[2];   // (256,)
    float* out = (float*)d_out;

    unsigned short* wt2 = (unsigned short*)d_ws;   // 294,912 elems = 590 KB

    wpose_kernel<<<(36 * 16 * 64 * 8 + 255) / 256, 256, 0, stream>>>(wk, wt2);
    dim3 gc(14, NB);                               // 4 output rows per block
    conv_mfma_kernel<<<gc, 512, 0, stream>>>(x, wt2, b, out);
    (void)ws_size; (void)in_sizes; (void)n_in; (void)out_size;
}

// Round 20
// 70.638 us; speedup vs baseline: 1.1175x; 1.0332x over previous
//
#include <hip/hip_runtime.h>
#include <hip/hip_bf16.h>

#define NB   32
#define CIN  128
#define COUT 256
#define HH   56
#define WW   56
#define CH   59        // padded B-row length in 16B chunks (944 = 16*59)

typedef __attribute__((ext_vector_type(8))) short short8;   // 8 bf16 (4 VGPRs)
typedef __attribute__((ext_vector_type(4))) float f32x4;    // MFMA accumulator

// round-to-nearest-even fp32 -> bf16 (raw u16)
__device__ __forceinline__ unsigned short f2bf(float f) {
    unsigned int u = __builtin_bit_cast(unsigned int, f);
    u = u + 0x7fffu + ((u >> 16) & 1u);
    return (unsigned short)(u >> 16);
}

// async global->LDS, 16B per lane; LDS dest = wave-uniform base + lane*16
__device__ __forceinline__ void glds16(const unsigned short* g, unsigned short* l) {
    __builtin_amdgcn_global_load_lds(
        (const __attribute__((address_space(1))) unsigned int*)g,
        (__attribute__((address_space(3))) unsigned int*)l,
        16, 0, 0);
}

// ---------------------------------------------------------------------------
// Pre-pass: weights OIHW f32 -> wt2 in EXACT MFMA A-fragment order:
//   chunk ((s*16 + f)*64 + lane), elem j:  w[o=f*16+r][c=cc*32+g*8+j][tap t]
//   (s = K-step: t = s>>2, cc = s&3;  lane: g = lane>>4, r = lane&15)
// ---------------------------------------------------------------------------
__global__ __launch_bounds__(256) void wpose_kernel(const float* __restrict__ w,
                                                    unsigned short* __restrict__ wt2) {
    int q = blockIdx.x * 256 + threadIdx.x;
    if (q >= 36 * 16 * 64 * 8) return;
    int j = q & 7;
    int l = (q >> 3) & 63;
    int f = (q >> 9) & 15;
    int s = q >> 13;
    int g = l >> 4, r = l & 15;
    int t = s >> 2, cc = s & 3;
    int o = f * 16 + r;
    int c = cc * 32 + g * 8 + j;
    wt2[q] = f2bf(w[((size_t)o * CIN + c) * 9 + t]);
}

// ---------------------------------------------------------------------------
// Main conv (= measured-best r19 + XCD-chunked block swizzle):
// block = 256 Cout x 224 spatial (4 output rows h0..h0+3), 512 threads =
// 8 waves as 4(M) x 2(N); wave = 64 Cout x 112 cols (4 M-frags x 7 N-frags
// of 16x16x32 -- the unique port-balanced point at 2 waves/SIMD).
// 36 K-steps, barrier-free.
//
// T1 swizzle: 1-D grid of 448 (= 8*56 exactly -> bijective); dispatch id d
// (XCD d%8 under round-robin) processes tile swz = (d&7)*56 + d>>3, so each
// XCD gets 56 consecutive tiles = 4 COMPLETE images: halo rows (2/6 shared
// between adjacent-h blocks) and the 576 KB weight stream become L2-local.
//
//   A: per-wave private LDS ring (2 slots x 4 frags) fed by global_load_lds,
//      ordered by per-wave `s_waitcnt vmcnt(4)` only -- NO s_barrier.
//   B: x rows h0-1..h0+4 transposed in-block, float4-vectorized, staged ONCE:
//      chunk ((row*16+gc)*59 + wpos), 8 ch; wpos 0/57/58 + OOB rows = 0.
//      All K-loop B addressing = 16-bit ds_read immediates.
//   + distance-1 B-register double-buffer.
// LDS = 90624 (B) + 65536 (A-ring) = 156160 B.
// ---------------------------------------------------------------------------
__global__ __launch_bounds__(512, 2) void conv_mfma_kernel(
        const float* __restrict__ x,
        const unsigned short* __restrict__ wt2,
        const float* __restrict__ bias,
        float* __restrict__ out) {
    __shared__ unsigned short ldsB[6 * 16 * CH * 8];    // 90624 B
    __shared__ unsigned short ldsA[8 * 2 * 2048];       // 65536 B: [wave][slot][4KB]

    const int tid  = threadIdx.x;
    // ---- XCD-chunked bijective swizzle (448 = 8 XCDs x 56 tiles) ----
    const int bid  = blockIdx.x;
    const int swz  = (bid & 7) * 56 + (bid >> 3);
    const int n    = swz / 14;
    const int h0   = (swz - n * 14) * 4;
    const int wid  = tid >> 6, lane = tid & 63;
    const int wm   = wid >> 1, wn = wid & 1;            // 4M x 2N wave grid
    const int g    = lane >> 4, r = lane & 15;

    // ---- zero B chunks (pads + OOB rows stay zero) ----
    for (int i = tid; i < 6 * 16 * CH; i += 512) {
        uint4 z = {0u, 0u, 0u, 0u};
        *(uint4*)&ldsB[(size_t)i * 8] = z;
    }
    __syncthreads();

    // ---- fused transpose, float4-vectorized: unit = (row, cp, w4) ----
    {
        const float* xn = x + (size_t)n * CIN * HH * WW;
        for (int i = tid; i < 6 * 64 * 14; i += 512) {   // 5376 units
            int w4  = i % 14;
            int t1  = i / 14;
            int cp  = t1 & 63;                  // channel pair: c = 2cp, 2cp+1
            int row = t1 >> 6;                  // 0..5 -> input row h0+row-1
            int hs  = h0 + row - 1;
            if ((unsigned)hs < HH) {
                const float* p = xn + ((size_t)(2 * cp) * HH + hs) * WW + 4 * w4;
                float4 va = *(const float4*)p;
                float4 vb = *(const float4*)(p + HH * WW);
                int gc = cp >> 2, e = cp & 3;
                #pragma unroll
                for (int j = 0; j < 4; ++j) {
                    int wpos = 4 * w4 + j + 1;
                    unsigned int pk = (unsigned int)f2bf(((const float*)&va)[j])
                                    | ((unsigned int)f2bf(((const float*)&vb)[j]) << 16);
                    ((unsigned int*)ldsB)[((row * 16 + gc) * CH + wpos) * 4 + e] = pk;
                }
            }
        }
    }

    // ---- A-ring stage: wave wid's 4 frags (f = wm*4+mi) for step s -> slot ----
    unsigned short* aslot = &ldsA[(size_t)wid * 2 * 2048];
    #define STAGE_A(slot, s)                                                    \
        {                                                                       \
            const unsigned short* asrc_ =                                       \
                wt2 + ((size_t)(s) * 16 + wm * 4) * 512 + lane * 8;             \
            unsigned short* adst_ = aslot + (slot) * 2048;                      \
            glds16(asrc_,        adst_);                                        \
            glds16(asrc_ + 512,  adst_ + 512);                                  \
            glds16(asrc_ + 1024, adst_ + 1024);                                 \
            glds16(asrc_ + 1536, adst_ + 1536);                                 \
        }

    STAGE_A(0, 0);
    __syncthreads();    // drains transpose writes AND slot-0 glds; last barrier

    // per-lane B base pointers for the 7 N-fragments
    const unsigned short* bbase[7];
    #pragma unroll
    for (int ni = 0; ni < 7; ++ni) {
        int c  = ni * 16 + r;
        int hr = (c >= 56) ? 1 : 0;
        int lo = hr * (16 * CH) + (c - hr * 56);
        bbase[ni] = &ldsB[(size_t)((wn * 32 + g) * CH + lo) * 8];
    }

    f32x4 acc[4][7];
    #pragma unroll
    for (int mi = 0; mi < 4; ++mi)
        #pragma unroll
        for (int ni = 0; ni < 7; ++ni)
            #pragma unroll
            for (int v = 0; v < 4; ++v) acc[mi][ni][v] = 0.f;

    const unsigned short* aread = aslot + lane * 8;   // + slot*2048 + mi*512

    // ---- distance-1 B-register double-buffer ----
    short8 bcur[7], bnxt[7];
    #define LOAD_B(dst, s_)                                                     \
        {                                                                       \
            const int t_ = (s_) >> 2, cc_ = (s_) & 3;                           \
            const int kh_ = t_ / 3, kw_ = t_ - 3 * (t_ / 3);                    \
            const int boff_ = kh_ * 15104 + cc_ * 3776 + kw_ * 16;              \
            _Pragma("unroll")                                                   \
            for (int ni = 0; ni < 7; ++ni)                                      \
                dst[ni] = *(const short8*)((const char*)bbase[ni] + boff_);     \
        }

    LOAD_B(bcur, 0);

    #pragma unroll
    for (int s = 0; s < 36; ++s) {
        const int p = s & 1;

        if (s < 35) STAGE_A(p ^ 1, s + 1);      // next A slice (async glds)
        if (s < 35) {                           // next B frags (ds_reads issue
            if (p == 0) { LOAD_B(bnxt, s + 1); }//  before this step's MFMAs)
            else        { LOAD_B(bcur, s + 1); }
        }

        // wait: step-s's 4 glds landed (s+1's 4 may stay in flight)
        if (s < 35) asm volatile("s_waitcnt vmcnt(4)" ::: "memory");
        else        asm volatile("s_waitcnt vmcnt(0)" ::: "memory");

        short8 a[4];
        #pragma unroll
        for (int mi = 0; mi < 4; ++mi)
            a[mi] = *(const short8*)(aread + p * 2048 + mi * 512);

        #pragma unroll
        for (int mi = 0; mi < 4; ++mi)
            #pragma unroll
            for (int ni = 0; ni < 7; ++ni)
                acc[mi][ni] = __builtin_amdgcn_mfma_f32_16x16x32_bf16(
                    a[mi], (p == 0) ? bcur[ni] : bnxt[ni], acc[mi][ni], 0, 0, 0);
    }

    // ---- epilogue: D col = r (spatial), row = g*4+v (Cout within frag) ----
    #pragma unroll
    for (int mi = 0; mi < 4; ++mi) {
        const int o0 = wm * 64 + mi * 16 + 4 * g;
        const float4 bv = *(const float4*)&bias[o0];
        #pragma unroll
        for (int ni = 0; ni < 7; ++ni) {
            const int c  = ni * 16 + r;
            const int hr = (c >= 56) ? 1 : 0;
            const int h  = h0 + wn * 2 + hr;
            const int w  = c - hr * 56;
            #pragma unroll
            for (int v = 0; v < 4; ++v) {
                out[((size_t)(n * COUT + o0 + v) * HH + h) * WW + w] =
                    acc[mi][ni][v] + ((const float*)&bv)[v];
            }
        }
    }
}

extern "C" void kernel_launch(void* const* d_in, const int* in_sizes, int n_in,
                              void* d_out, int out_size, void* d_ws, size_t ws_size,
                              hipStream_t stream) {
    const float* x  = (const float*)d_in[0];   // (32,128,56,56)
    const float* wk = (const float*)d_in[1];   // (256,128,3,3)
    const float* b  = (const float*)d_in[2];   // (256,)
    float* out = (float*)d_out;

    unsigned short* wt2 = (unsigned short*)d_ws;   // 294,912 elems = 590 KB

    wpose_kernel<<<(36 * 16 * 64 * 8 + 255) / 256, 256, 0, stream>>>(wk, wt2);
    conv_mfma_kernel<<<448, 512, 0, stream>>>(x, wt2, b, out);
    (void)ws_size; (void)in_sizes; (void)n_in; (void)out_size;
}

// Round 21
// 70.302 us; speedup vs baseline: 1.1228x; 1.0048x over previous
//
#include <hip/hip_runtime.h>
#include <hip/hip_bf16.h>

#define NB   32
#define CIN  128
#define COUT 256
#define HH   56
#define WW   56
#define CH   59        // padded B-row length in 16B chunks (944 = 16*59)

typedef __attribute__((ext_vector_type(8))) short short8;   // 8 bf16 (4 VGPRs)
typedef __attribute__((ext_vector_type(4))) float f32x4;    // MFMA accumulator

// round-to-nearest-even fp32 -> bf16 (raw u16)
__device__ __forceinline__ unsigned short f2bf(float f) {
    unsigned int u = __builtin_bit_cast(unsigned int, f);
    u = u + 0x7fffu + ((u >> 16) & 1u);
    return (unsigned short)(u >> 16);
}

// async global->LDS, 16B per lane; LDS dest = wave-uniform base + lane*16
__device__ __forceinline__ void glds16(const unsigned short* g, unsigned short* l) {
    __builtin_amdgcn_global_load_lds(
        (const __attribute__((address_space(1))) unsigned int*)g,
        (__attribute__((address_space(3))) unsigned int*)l,
        16, 0, 0);
}

// ---------------------------------------------------------------------------
// Pre-pass: weights OIHW f32 -> wt2 in EXACT MFMA A-fragment order:
//   chunk ((s*16 + f)*64 + lane), elem j:  w[o=f*16+r][c=cc*32+g*8+j][tap t]
//   (s = K-step: t = s>>2, cc = s&3;  lane: g = lane>>4, r = lane&15)
// ---------------------------------------------------------------------------
__global__ __launch_bounds__(256) void wpose_kernel(const float* __restrict__ w,
                                                    unsigned short* __restrict__ wt2) {
    int q = blockIdx.x * 256 + threadIdx.x;
    if (q >= 36 * 16 * 64 * 8) return;
    int j = q & 7;
    int l = (q >> 3) & 63;
    int f = (q >> 9) & 15;
    int s = q >> 13;
    int g = l >> 4, r = l & 15;
    int t = s >> 2, cc = s & 3;
    int o = f * 16 + r;
    int c = cc * 32 + g * 8 + j;
    wt2[q] = f2bf(w[((size_t)o * CIN + c) * 9 + t]);
}

// ---------------------------------------------------------------------------
// Main conv (= r20 measured-best + pad-only LDS zeroing):
// block = 256 Cout x 224 spatial (4 output rows h0..h0+3), 512 threads =
// 8 waves as 4(M) x 2(N); wave = 64 Cout x 112 cols (4 M-frags x 7 N-frags
// of 16x16x32 -- the unique port-balanced point at 2 waves/SIMD).
// 36 K-steps, barrier-free.
//
// T1 swizzle: 1-D grid of 448 (= 8*56 -> bijective); XCD d%8 gets 56
// consecutive tiles = 4 complete images -> halo rows + weight stream
// are L2-local (measured: FETCH 43.2 -> 30.2 MB, -2.3 us).
//
//   A: per-wave private LDS ring (2 slots x 4 frags) fed by global_load_lds,
//      ordered by per-wave `s_waitcnt vmcnt(4)` only -- NO s_barrier.
//   B: x rows h0-1..h0+4 transposed in-block, float4-vectorized, staged ONCE:
//      chunk ((row*16+gc)*59 + wpos), 8 ch; wpos 0/57/58 + OOB rows zeroed
//      (pad-only zeroing: 288 + boundary chunks, not all 5664).
//      All K-loop B addressing = 16-bit ds_read immediates.
//   + distance-1 B-register double-buffer.
// LDS = 90624 (B) + 65536 (A-ring) = 156160 B.
// ---------------------------------------------------------------------------
__global__ __launch_bounds__(512, 2) void conv_mfma_kernel(
        const float* __restrict__ x,
        const unsigned short* __restrict__ wt2,
        const float* __restrict__ bias,
        float* __restrict__ out) {
    __shared__ unsigned short ldsB[6 * 16 * CH * 8];    // 90624 B
    __shared__ unsigned short ldsA[8 * 2 * 2048];       // 65536 B: [wave][slot][4KB]

    const int tid  = threadIdx.x;
    // ---- XCD-chunked bijective swizzle (448 = 8 XCDs x 56 tiles) ----
    const int bid  = blockIdx.x;
    const int swz  = (bid & 7) * 56 + (bid >> 3);
    const int n    = swz / 14;
    const int h0   = (swz - n * 14) * 4;
    const int wid  = tid >> 6, lane = tid & 63;
    const int wm   = wid >> 1, wn = wid & 1;            // 4M x 2N wave grid
    const int g    = lane >> 4, r = lane & 15;

    const uint4 z = {0u, 0u, 0u, 0u};

    // ---- zero ONLY pad chunks (wpos 0,57,58 all rows) + OOB rows ----
    if (tid < 288) {                        // 6 rows x 16 gc x {0,57,58}
        int row = tid / 48, sub = tid % 48;
        int gc = sub / 3, k3 = sub % 3;
        int wp = (k3 == 0) ? 0 : (56 + k3);
        *(uint4*)&ldsB[(size_t)((row * 16 + gc) * CH + wp) * 8] = z;
    }
    if (h0 == 0) {                          // input row h0-1 OOB -> row 0 = 0
        for (int i = tid; i < 16 * CH; i += 512)
            *(uint4*)&ldsB[(size_t)i * 8] = z;
    }
    if (h0 == 52) {                         // input row h0+4 OOB -> row 5 = 0
        for (int i = tid; i < 16 * CH; i += 512)
            *(uint4*)&ldsB[(size_t)(5 * 16 * CH + i) * 8] = z;
    }

    // ---- fused transpose, float4-vectorized: unit = (row, cp, w4) ----
    {
        const float* xn = x + (size_t)n * CIN * HH * WW;
        for (int i = tid; i < 6 * 64 * 14; i += 512) {   // 5376 units
            int w4  = i % 14;
            int t1  = i / 14;
            int cp  = t1 & 63;                  // channel pair: c = 2cp, 2cp+1
            int row = t1 >> 6;                  // 0..5 -> input row h0+row-1
            int hs  = h0 + row - 1;
            if ((unsigned)hs < HH) {
                const float* p = xn + ((size_t)(2 * cp) * HH + hs) * WW + 4 * w4;
                float4 va = *(const float4*)p;
                float4 vb = *(const float4*)(p + HH * WW);
                int gc = cp >> 2, e = cp & 3;
                #pragma unroll
                for (int j = 0; j < 4; ++j) {
                    int wpos = 4 * w4 + j + 1;
                    unsigned int pk = (unsigned int)f2bf(((const float*)&va)[j])
                                    | ((unsigned int)f2bf(((const float*)&vb)[j]) << 16);
                    ((unsigned int*)ldsB)[((row * 16 + gc) * CH + wpos) * 4 + e] = pk;
                }
            }
        }
    }

    // ---- A-ring stage: wave wid's 4 frags (f = wm*4+mi) for step s -> slot ----
    unsigned short* aslot = &ldsA[(size_t)wid * 2 * 2048];
    #define STAGE_A(slot, s)                                                    \
        {                                                                       \
            const unsigned short* asrc_ =                                       \
                wt2 + ((size_t)(s) * 16 + wm * 4) * 512 + lane * 8;             \
            unsigned short* adst_ = aslot + (slot) * 2048;                      \
            glds16(asrc_,        adst_);                                        \
            glds16(asrc_ + 512,  adst_ + 512);                                  \
            glds16(asrc_ + 1024, adst_ + 1024);                                 \
            glds16(asrc_ + 1536, adst_ + 1536);                                 \
        }

    STAGE_A(0, 0);
    __syncthreads();    // drains transpose writes AND slot-0 glds; last barrier

    // per-lane B base pointers for the 7 N-fragments
    const unsigned short* bbase[7];
    #pragma unroll
    for (int ni = 0; ni < 7; ++ni) {
        int c  = ni * 16 + r;
        int hr = (c >= 56) ? 1 : 0;
        int lo = hr * (16 * CH) + (c - hr * 56);
        bbase[ni] = &ldsB[(size_t)((wn * 32 + g) * CH + lo) * 8];
    }

    f32x4 acc[4][7];
    #pragma unroll
    for (int mi = 0; mi < 4; ++mi)
        #pragma unroll
        for (int ni = 0; ni < 7; ++ni)
            #pragma unroll
            for (int v = 0; v < 4; ++v) acc[mi][ni][v] = 0.f;

    const unsigned short* aread = aslot + lane * 8;   // + slot*2048 + mi*512

    // ---- distance-1 B-register double-buffer ----
    short8 bcur[7], bnxt[7];
    #define LOAD_B(dst, s_)                                                     \
        {                                                                       \
            const int t_ = (s_) >> 2, cc_ = (s_) & 3;                           \
            const int kh_ = t_ / 3, kw_ = t_ - 3 * (t_ / 3);                    \
            const int boff_ = kh_ * 15104 + cc_ * 3776 + kw_ * 16;              \
            _Pragma("unroll")                                                   \
            for (int ni = 0; ni < 7; ++ni)                                      \
                dst[ni] = *(const short8*)((const char*)bbase[ni] + boff_);     \
        }

    LOAD_B(bcur, 0);

    #pragma unroll
    for (int s = 0; s < 36; ++s) {
        const int p = s & 1;

        if (s < 35) STAGE_A(p ^ 1, s + 1);      // next A slice (async glds)
        if (s < 35) {                           // next B frags (ds_reads issue
            if (p == 0) { LOAD_B(bnxt, s + 1); }//  before this step's MFMAs)
            else        { LOAD_B(bcur, s + 1); }
        }

        // wait: step-s's 4 glds landed (s+1's 4 may stay in flight)
        if (s < 35) asm volatile("s_waitcnt vmcnt(4)" ::: "memory");
        else        asm volatile("s_waitcnt vmcnt(0)" ::: "memory");

        short8 a[4];
        #pragma unroll
        for (int mi = 0; mi < 4; ++mi)
            a[mi] = *(const short8*)(aread + p * 2048 + mi * 512);

        #pragma unroll
        for (int mi = 0; mi < 4; ++mi)
            #pragma unroll
            for (int ni = 0; ni < 7; ++ni)
                acc[mi][ni] = __builtin_amdgcn_mfma_f32_16x16x32_bf16(
                    a[mi], (p == 0) ? bcur[ni] : bnxt[ni], acc[mi][ni], 0, 0, 0);
    }

    // ---- epilogue: D col = r (spatial), row = g*4+v (Cout within frag) ----
    #pragma unroll
    for (int mi = 0; mi < 4; ++mi) {
        const int o0 = wm * 64 + mi * 16 + 4 * g;
        const float4 bv = *(const float4*)&bias[o0];
        #pragma unroll
        for (int ni = 0; ni < 7; ++ni) {
            const int c  = ni * 16 + r;
            const int hr = (c >= 56) ? 1 : 0;
            const int h  = h0 + wn * 2 + hr;
            const int w  = c - hr * 56;
            #pragma unroll
            for (int v = 0; v < 4; ++v) {
                out[((size_t)(n * COUT + o0 + v) * HH + h) * WW + w] =
                    acc[mi][ni][v] + ((const float*)&bv)[v];
            }
        }
    }
}

extern "C" void kernel_launch(void* const* d_in, const int* in_sizes, int n_in,
                              void* d_out, int out_size, void* d_ws, size_t ws_size,
                              hipStream_t stream) {
    const float* x  = (const float*)d_in[0];   // (32,128,56,56)
    const float* wk = (const float*)d_in[1];   // (256,128,3,3)
    const float* b  = (const float*)d_in[2];   // (256,)
    float* out = (float*)d_out;

    unsigned short* wt2 = (unsigned short*)d_ws;   // 294,912 elems = 590 KB

    wpose_kernel<<<(36 * 16 * 64 * 8 + 255) / 256, 256, 0, stream>>>(wk, wt2);
    conv_mfma_kernel<<<448, 512, 0, stream>>>(x, wt2, b, out);
    (void)ws_size; (void)in_sizes; (void)n_in; (void)out_size;
}